// Round 1
// baseline (319.412 us; speedup 1.0000x reference)
//
#include <hip/hip_runtime.h>
#include <hip/hip_bf16.h>

#define NEG (-1e30f)

constexpr int Bc = 16, Tc = 1000, Vc = 4096, Sc = 100;
constexpr int Lpad = 256;  // padded extended-label length (L = 2*S+1 = 201)

// Kernel 1: per (b,t) logsumexp over V, then gather the 201 extended-label
// log-probs into lp[b][t][0..200] (s>200 -> NEG).
__global__ __launch_bounds__(256) void k_lse_gather(
    const float* __restrict__ x, const int* __restrict__ y,
    float* __restrict__ lp)
{
  int bt = blockIdx.x;  // b*T + t
  int b = bt / Tc;
  int tid = threadIdx.x;
  const float4* row4 = (const float4*)(x + (size_t)bt * Vc);
  __shared__ float sh[Vc];
  __shared__ float red[8];
  float4* sh4 = (float4*)sh;
  float4 v[4];
  float mx = -3.4e38f;
#pragma unroll
  for (int k = 0; k < 4; ++k) {
    v[k] = row4[k * 256 + tid];
    sh4[k * 256 + tid] = v[k];
    mx = fmaxf(mx, fmaxf(fmaxf(v[k].x, v[k].y), fmaxf(v[k].z, v[k].w)));
  }
#pragma unroll
  for (int off = 32; off; off >>= 1) mx = fmaxf(mx, __shfl_xor(mx, off));
  if ((tid & 63) == 0) red[tid >> 6] = mx;
  __syncthreads();
  mx = fmaxf(fmaxf(red[0], red[1]), fmaxf(red[2], red[3]));
  float s = 0.f;
#pragma unroll
  for (int k = 0; k < 4; ++k) {
    s += __expf(v[k].x - mx) + __expf(v[k].y - mx) +
         __expf(v[k].z - mx) + __expf(v[k].w - mx);
  }
#pragma unroll
  for (int off = 32; off; off >>= 1) s += __shfl_xor(s, off);
  if ((tid & 63) == 0) red[4 + (tid >> 6)] = s;
  __syncthreads();
  s = (red[4] + red[5]) + (red[6] + red[7]);
  float lse = mx + __logf(s);
  float out;
  if (tid <= 200) {
    int lab = (tid & 1) ? y[b * Sc + (tid >> 1)] : 0;  // z[s]: blank at even s
    out = sh[lab] - lse;
  } else {
    out = NEG;
  }
  lp[(size_t)bt * Lpad + tid] = out;
}

// Kernel 2: CTC forward DP. One wave per batch; lane holds states 4*lane..4*lane+3
// in registers. Only cross-lane dependency per step is prev lane's a3 (state 4L-1).
__global__ __launch_bounds__(64) void k_ctc_dp(
    const float* __restrict__ lp, const int* __restrict__ y,
    const int* __restrict__ f_len, const int* __restrict__ y_len,
    float* __restrict__ losses)
{
  int b = blockIdx.x;
  int lane = threadIdx.x;
  const float4* lpp = (const float4*)(lp + (size_t)b * Tc * Lpad);
  int F = f_len[b];
  const int* yb = y + b * Sc;
  // allow_skip for odd states: s=4L+1 -> y[2L] != y[2L-1]; s=4L+3 -> y[2L+1] != y[2L]
  int i0 = 2 * lane, i1i = 2 * lane + 1;
  int y_m1 = (i0 >= 1 && i0 - 1 < Sc) ? yb[i0 - 1] : -1;
  int y_0  = (i0 < Sc) ? yb[i0] : -2;
  int y_1  = (i1i < Sc) ? yb[i1i] : -3;
  bool allow1 = (y_0 != y_m1);  // lane 0: irrelevant, its p3 is NEG anyway
  bool allow3 = (y_1 != y_0);

  float4 f0 = lpp[lane];  // t = 0
  float a0 = (lane == 0) ? f0.x : NEG;
  float a1 = (lane == 0) ? f0.y : NEG;
  float a2r = NEG, a3r = NEG;

  float4 nxt = (F > 1) ? lpp[64 + lane] : f0;
  for (int t = 1; t < F; ++t) {
    float4 cur = nxt;
    if (t + 1 < F) nxt = lpp[(size_t)(t + 1) * 64 + lane];
    float up3 = __shfl_up(a3r, 1);  // state 4*lane - 1
    if (lane == 0) up3 = NEG;
    // j=0 (even s): preds {self, s-1}
    float m0 = fmaxf(a0, up3);
    float n0 = m0 + __logf(__expf(a0 - m0) + __expf(up3 - m0)) + cur.x;
    // j=1 (odd): preds {self, s-1, s-2 if allowed}
    float p3 = allow1 ? up3 : NEG;
    float m1 = fmaxf(fmaxf(a1, a0), p3);
    float n1 = m1 + __logf(__expf(a1 - m1) + __expf(a0 - m1) + __expf(p3 - m1)) + cur.y;
    // j=2 (even): preds {self, s-1}
    float m2 = fmaxf(a2r, a1);
    float n2 = m2 + __logf(__expf(a2r - m2) + __expf(a1 - m2)) + cur.z;
    // j=3 (odd): preds {self, s-1, s-2 if allowed}
    float q3 = allow3 ? a1 : NEG;
    float m3 = fmaxf(fmaxf(a3r, a2r), q3);
    float n3 = m3 + __logf(__expf(a3r - m3) + __expf(a2r - m3) + __expf(q3 - m3)) + cur.w;
    a0 = n0; a1 = n1; a2r = n2; a3r = n3;
  }

  __shared__ float sa[256];
  ((float4*)sa)[lane] = make_float4(a0, a1, a2r, a3r);
  __syncthreads();
  if (lane == 0) {
    int yl = y_len[b];
    int idx1 = 2 * yl;
    int idx2 = (2 * yl - 1 > 0) ? (2 * yl - 1) : 0;
    float A = sa[idx1], Bv = sa[idx2];
    float m = fmaxf(A, Bv);
    float loss = -(m + __logf(__expf(A - m) + __expf(Bv - m)));
    losses[b] = loss;
  }
}

// Kernel 3: zero_infinity + mean over B.
__global__ __launch_bounds__(64) void k_final(const float* __restrict__ losses,
                                              float* __restrict__ out)
{
  int tid = threadIdx.x;
  float v = (tid < Bc) ? losses[tid] : 0.f;
  v = (v < 1e29f) ? v : 0.f;
#pragma unroll
  for (int off = 32; off; off >>= 1) v += __shfl_xor(v, off);
  if (tid == 0) out[0] = v / (float)Bc;
}

extern "C" void kernel_launch(void* const* d_in, const int* in_sizes, int n_in,
                              void* d_out, int out_size, void* d_ws, size_t ws_size,
                              hipStream_t stream) {
  const float* x = (const float*)d_in[0];      // [B,T,V] f32
  const int* y = (const int*)d_in[1];          // [B,S]
  const int* f_len = (const int*)d_in[2];      // [B]
  const int* y_len = (const int*)d_in[3];      // [B]
  float* out = (float*)d_out;                  // scalar f32
  float* lp = (float*)d_ws;                    // [B,T,256] f32 = 16.38 MB
  float* losses = lp + (size_t)Bc * Tc * Lpad; // [B]

  k_lse_gather<<<dim3(Bc * Tc), dim3(256), 0, stream>>>(x, y, lp);
  k_ctc_dp<<<dim3(Bc), dim3(64), 0, stream>>>(lp, y, f_len, y_len, losses);
  k_final<<<dim3(1), dim3(64), 0, stream>>>(losses, out);
}

// Round 2
// 199.858 us; speedup vs baseline: 1.5982x; 1.5982x over previous
//
#include <hip/hip_runtime.h>
#include <hip/hip_bf16.h>

#define NEG (-1e30f)
#define LOG2E 1.4426950408889634f
#define LN2   0.6931471805599453f

constexpr int Bc = 16, Tc = 1000, Vc = 4096, Sc = 100;
constexpr int Lpad = 256;  // padded extended-label length (L = 2*S+1 = 201)

// Kernel 1: per (b,t) logsumexp over V, then gather the 201 extended-label
// log-probs (in LOG2 domain) into lp[b][t][0..200] (s>200 -> NEG).
__global__ __launch_bounds__(256) void k_lse_gather(
    const float* __restrict__ x, const int* __restrict__ y,
    float* __restrict__ lp)
{
  int bt = blockIdx.x;  // b*T + t
  int b = bt / Tc;
  int tid = threadIdx.x;
  const float4* row4 = (const float4*)(x + (size_t)bt * Vc);
  __shared__ float sh[Vc];
  __shared__ float red[8];
  float4* sh4 = (float4*)sh;
  float4 v[4];
  float mx = -3.4e38f;
#pragma unroll
  for (int k = 0; k < 4; ++k) {
    v[k] = row4[k * 256 + tid];
    sh4[k * 256 + tid] = v[k];
    mx = fmaxf(mx, fmaxf(fmaxf(v[k].x, v[k].y), fmaxf(v[k].z, v[k].w)));
  }
#pragma unroll
  for (int off = 32; off; off >>= 1) mx = fmaxf(mx, __shfl_xor(mx, off));
  if ((tid & 63) == 0) red[tid >> 6] = mx;
  __syncthreads();
  mx = fmaxf(fmaxf(red[0], red[1]), fmaxf(red[2], red[3]));
  float s = 0.f;
#pragma unroll
  for (int k = 0; k < 4; ++k) {
    s += __expf(v[k].x - mx) + __expf(v[k].y - mx) +
         __expf(v[k].z - mx) + __expf(v[k].w - mx);
  }
#pragma unroll
  for (int off = 32; off; off >>= 1) s += __shfl_xor(s, off);
  if ((tid & 63) == 0) red[4 + (tid >> 6)] = s;
  __syncthreads();
  s = (red[4] + red[5]) + (red[6] + red[7]);
  float lse = mx + __logf(s);
  float out;
  if (tid <= 200) {
    int lab = (tid & 1) ? y[b * Sc + (tid >> 1)] : 0;  // z[s]: blank at even s
    out = (sh[lab] - lse) * LOG2E;  // log2 domain for the DP
  } else {
    out = NEG;
  }
  lp[(size_t)bt * Lpad + tid] = out;
}

// Kernel 2: CTC forward DP in log2 domain. One wave per batch; lane holds
// states 4*lane..4*lane+3 in registers. Depth-8 register prefetch ring hides
// L3/HBM load latency (the round-1 bottleneck: ~660 cyc/step with depth 1).
__global__ __launch_bounds__(64) void k_ctc_dp(
    const float* __restrict__ lp, const int* __restrict__ y,
    const int* __restrict__ f_len, const int* __restrict__ y_len,
    float* __restrict__ losses)
{
  int b = blockIdx.x;
  int lane = threadIdx.x;
  const float4* lpp = (const float4*)(lp + (size_t)b * Tc * Lpad);
  int F = f_len[b];
  const int* yb = y + b * Sc;
  int i0 = 2 * lane, i1i = 2 * lane + 1;
  int y_m1 = (i0 >= 1 && i0 - 1 < Sc) ? yb[i0 - 1] : -1;
  int y_0  = (i0 < Sc) ? yb[i0] : -2;
  int y_1  = (i1i < Sc) ? yb[i1i] : -3;
  bool allow1 = (y_0 != y_m1);
  bool allow3 = (y_1 != y_0);

  float4 f0 = lpp[lane];  // t = 0
  float a0 = (lane == 0) ? f0.x : NEG;
  float a1 = (lane == 0) ? f0.y : NEG;
  float a2r = NEG, a3r = NEG;

#define EXP2(x) __builtin_amdgcn_exp2f(x)
#define LOG2(x) __builtin_amdgcn_logf(x)

#define STEP(CUR)                                                              \
  {                                                                            \
    float up3 = __shfl_up(a3r, 1);                                             \
    if (lane == 0) up3 = NEG;                                                  \
    float m0 = fmaxf(a0, up3);                                                 \
    float n0 = m0 + LOG2(EXP2(a0 - m0) + EXP2(up3 - m0)) + (CUR).x;            \
    float p3 = allow1 ? up3 : NEG;                                             \
    float m1 = fmaxf(fmaxf(a1, a0), p3);                                       \
    float n1 = m1 + LOG2(EXP2(a1 - m1) + EXP2(a0 - m1) + EXP2(p3 - m1)) +      \
               (CUR).y;                                                        \
    float m2 = fmaxf(a2r, a1);                                                 \
    float n2 = m2 + LOG2(EXP2(a2r - m2) + EXP2(a1 - m2)) + (CUR).z;            \
    float q3 = allow3 ? a1 : NEG;                                              \
    float m3 = fmaxf(fmaxf(a3r, a2r), q3);                                     \
    float n3 = m3 + LOG2(EXP2(a3r - m3) + EXP2(a2r - m3) + EXP2(q3 - m3)) +    \
               (CUR).w;                                                        \
    a0 = n0; a1 = n1; a2r = n2; a3r = n3;                                      \
  }

#define LOADK(BUF, T)                                                          \
  {                                                                            \
    int tt = (T); tt = tt < Tc ? tt : (Tc - 1);                                \
    BUF = lpp[(size_t)tt * 64 + lane];                                         \
  }

  float4 buf0, buf1, buf2, buf3, buf4, buf5, buf6, buf7;
  LOADK(buf0, 1); LOADK(buf1, 2); LOADK(buf2, 3); LOADK(buf3, 4);
  LOADK(buf4, 5); LOADK(buf5, 6); LOADK(buf6, 7); LOADK(buf7, 8);

  int t = 1;
  for (; t + 8 <= F; t += 8) {
    float4 c0 = buf0; LOADK(buf0, t + 8);  STEP(c0);
    float4 c1 = buf1; LOADK(buf1, t + 9);  STEP(c1);
    float4 c2 = buf2; LOADK(buf2, t + 10); STEP(c2);
    float4 c3 = buf3; LOADK(buf3, t + 11); STEP(c3);
    float4 c4 = buf4; LOADK(buf4, t + 12); STEP(c4);
    float4 c5 = buf5; LOADK(buf5, t + 13); STEP(c5);
    float4 c6 = buf6; LOADK(buf6, t + 14); STEP(c6);
    float4 c7 = buf7; LOADK(buf7, t + 15); STEP(c7);
  }
  for (; t < F; ++t) {
    float4 cur; LOADK(cur, t);
    STEP(cur);
  }

  __shared__ float sa[256];
  ((float4*)sa)[lane] = make_float4(a0, a1, a2r, a3r);
  __syncthreads();
  if (lane == 0) {
    int yl = y_len[b];
    int idx1 = 2 * yl;
    int idx2 = (2 * yl - 1 > 0) ? (2 * yl - 1) : 0;
    float A = sa[idx1], Bv = sa[idx2];
    float m = fmaxf(A, Bv);
    float loss = -(m + LOG2(EXP2(A - m) + EXP2(Bv - m))) * LN2;
    losses[b] = loss;
  }
}

// Kernel 3: zero_infinity + mean over B.
__global__ __launch_bounds__(64) void k_final(const float* __restrict__ losses,
                                              float* __restrict__ out)
{
  int tid = threadIdx.x;
  float v = (tid < Bc) ? losses[tid] : 0.f;
  v = (v < 1e29f) ? v : 0.f;
#pragma unroll
  for (int off = 32; off; off >>= 1) v += __shfl_xor(v, off);
  if (tid == 0) out[0] = v / (float)Bc;
}

extern "C" void kernel_launch(void* const* d_in, const int* in_sizes, int n_in,
                              void* d_out, int out_size, void* d_ws, size_t ws_size,
                              hipStream_t stream) {
  const float* x = (const float*)d_in[0];      // [B,T,V] f32
  const int* y = (const int*)d_in[1];          // [B,S]
  const int* f_len = (const int*)d_in[2];      // [B]
  const int* y_len = (const int*)d_in[3];      // [B]
  float* out = (float*)d_out;                  // scalar f32
  float* lp = (float*)d_ws;                    // [B,T,256] f32 = 16.38 MB
  float* losses = lp + (size_t)Bc * Tc * Lpad; // [B]

  k_lse_gather<<<dim3(Bc * Tc), dim3(256), 0, stream>>>(x, y, lp);
  k_ctc_dp<<<dim3(Bc), dim3(64), 0, stream>>>(lp, y, f_len, y_len, losses);
  k_final<<<dim3(1), dim3(64), 0, stream>>>(losses, out);
}

// Round 6
// 199.595 us; speedup vs baseline: 1.6003x; 1.0013x over previous
//
#include <hip/hip_runtime.h>
#include <hip/hip_bf16.h>

#define LN2D 0.6931471805599453

constexpr int Bc = 16, Tc = 1000, Vc = 4096, Sc = 100;
constexpr int Lpad = 256;  // padded extended-label length (L = 2*S+1 = 201)

// Kernel 1: per (b,t) softmax over V, gather the 201 extended-label probs
// (LINEAR domain, f32) into lp[b][t][0..255] (s>200 -> 0).
// Structure identical to the round-2 PASSING k_lse_gather; only the last
// two lines differ (exp instead of log2-scale).
__global__ __launch_bounds__(256) void k_prob_gather(
    const float* __restrict__ x, const int* __restrict__ y,
    float* __restrict__ lp)
{
  int bt = blockIdx.x;  // b*T + t
  int b = bt / Tc;
  int tid = threadIdx.x;
  const float4* row4 = (const float4*)(x + (size_t)bt * Vc);
  __shared__ float sh[Vc];
  __shared__ float red[8];
  float4* sh4 = (float4*)sh;
  float4 v[4];
  float mx = -3.4e38f;
#pragma unroll
  for (int k = 0; k < 4; ++k) {
    v[k] = row4[k * 256 + tid];
    sh4[k * 256 + tid] = v[k];
    mx = fmaxf(mx, fmaxf(fmaxf(v[k].x, v[k].y), fmaxf(v[k].z, v[k].w)));
  }
#pragma unroll
  for (int off = 32; off; off >>= 1) mx = fmaxf(mx, __shfl_xor(mx, off));
  if ((tid & 63) == 0) red[tid >> 6] = mx;
  __syncthreads();
  mx = fmaxf(fmaxf(red[0], red[1]), fmaxf(red[2], red[3]));
  float s = 0.f;
#pragma unroll
  for (int k = 0; k < 4; ++k) {
    s += __expf(v[k].x - mx) + __expf(v[k].y - mx) +
         __expf(v[k].z - mx) + __expf(v[k].w - mx);
  }
#pragma unroll
  for (int off = 32; off; off >>= 1) s += __shfl_xor(s, off);
  if ((tid & 63) == 0) red[4 + (tid >> 6)] = s;
  __syncthreads();
  s = (red[4] + red[5]) + (red[6] + red[7]);
  float lse = mx + __logf(s);
  float p;
  if (tid <= 200) {
    int lab = (tid & 1) ? y[b * Sc + (tid >> 1)] : 0;  // z[s]: blank at even s
    p = __expf(sh[lab] - lse);
  } else {
    p = 0.f;  // dead states
  }
  lp[(size_t)bt * Lpad + tid] = p;
}

// Kernel 2: scaled-forward CTC DP, alphas in f64 (no transcendentals in the
// loop). One wave per batch; lane holds states 4L..4L+3. Cross-lane a3 via
// __shfl_up (PROVEN in rounds 1/2 — the DPP replacement was the rounds-3/4/5
// failure). Exact global 2^{-e} rescale every 8 steps; exponent K exact-int.
__global__ __launch_bounds__(64) void k_ctc_dp(
    const float* __restrict__ lp, const int* __restrict__ y,
    const int* __restrict__ f_len, const int* __restrict__ y_len,
    float* __restrict__ losses)
{
  int b = blockIdx.x;
  int lane = threadIdx.x;
  const float4* lpp = (const float4*)(lp + (size_t)b * Tc * Lpad);
  int F = f_len[b];
  const int* yb = y + b * Sc;
  int i0 = 2 * lane, i1i = 2 * lane + 1;
  int y_m1 = (i0 >= 1 && i0 - 1 < Sc) ? yb[i0 - 1] : -1;
  int y_0  = (i0 < Sc) ? yb[i0] : -2;
  int y_1  = (i1i < Sc) ? yb[i1i] : -3;
  bool allow1 = (y_0 != y_m1);
  bool allow3 = (y_1 != y_0);
  int K = 0;  // true alpha = ahat * 2^{-K}; identical in all lanes

  // init t=0
  float4 r0 = lpp[lane];
  double a0 = (lane == 0) ? (double)r0.x : 0.0;
  double a1 = (lane == 0) ? (double)r0.y : 0.0;
  double a2 = 0.0, a3 = 0.0;

#define STEP(CUR)                                                              \
  {                                                                            \
    double up3 = __shfl_up(a3, 1);                                             \
    if (lane == 0) up3 = 0.0;                                                  \
    double px = (double)(CUR).x, py = (double)(CUR).y;                         \
    double pz = (double)(CUR).z, pw = (double)(CUR).w;                         \
    double n0 = (a0 + up3) * px;                                               \
    double n1 = (a1 + a0 + (allow1 ? up3 : 0.0)) * py;                         \
    double n2 = (a2 + a1) * pz;                                                \
    double n3 = (a3 + a2 + (allow3 ? a1 : 0.0)) * pw;                          \
    a0 = n0; a1 = n1; a2 = n2; a3 = n3;                                        \
  }

  // Exact global power-of-2 rescale. Positive-double hi-words compare as
  // ints; zero states give hi=0 which never wins the max (global max > 0:
  // after each rescale the dominant state is ~1).
#define RESCALE                                                                \
  {                                                                            \
    int _h = max(max(__double2hiint(a0), __double2hiint(a1)),                  \
                 max(__double2hiint(a2), __double2hiint(a3)));                 \
    _h = max(_h, __shfl_xor(_h, 1));                                           \
    _h = max(_h, __shfl_xor(_h, 2));                                           \
    _h = max(_h, __shfl_xor(_h, 4));                                           \
    _h = max(_h, __shfl_xor(_h, 8));                                           \
    _h = max(_h, __shfl_xor(_h, 16));                                          \
    _h = max(_h, __shfl_xor(_h, 32));                                          \
    int _e = (_h >> 20) - 1023;                                                \
    double _sc = __hiloint2double((1023 - _e) << 20, 0); /* exact 2^{-e} */    \
    a0 *= _sc; a1 *= _sc; a2 *= _sc; a3 *= _sc;                                \
    K -= _e;                                                                   \
  }

#define LOADK(BUF, T)                                                          \
  {                                                                            \
    int tt = (T); tt = tt < Tc ? tt : (Tc - 1);                                \
    BUF = lpp[(size_t)tt * 64 + lane];                                         \
  }

  float4 buf0, buf1, buf2, buf3, buf4, buf5, buf6, buf7;
  LOADK(buf0, 1); LOADK(buf1, 2); LOADK(buf2, 3); LOADK(buf3, 4);
  LOADK(buf4, 5); LOADK(buf5, 6); LOADK(buf6, 7); LOADK(buf7, 8);

  int t = 1;
  for (; t + 8 <= F; t += 8) {
    float4 c0 = buf0; LOADK(buf0, t + 8);  STEP(c0);
    float4 c1 = buf1; LOADK(buf1, t + 9);  STEP(c1);
    float4 c2 = buf2; LOADK(buf2, t + 10); STEP(c2);
    float4 c3 = buf3; LOADK(buf3, t + 11); STEP(c3);
    float4 c4 = buf4; LOADK(buf4, t + 12); STEP(c4);
    float4 c5 = buf5; LOADK(buf5, t + 13); STEP(c5);
    float4 c6 = buf6; LOADK(buf6, t + 14); STEP(c6);
    float4 c7 = buf7; LOADK(buf7, t + 15); STEP(c7);
    RESCALE;
  }
  for (; t < F; ++t) {
    float4 cur; LOADK(cur, t);
    STEP(cur);
  }

  __shared__ double sa[256];
  sa[4 * lane + 0] = a0;
  sa[4 * lane + 1] = a1;
  sa[4 * lane + 2] = a2;
  sa[4 * lane + 3] = a3;
  __syncthreads();
  if (lane == 0) {
    int yl = y_len[b];
    int idx2 = (2 * yl - 1 > 0) ? (2 * yl - 1) : 0;
    double s = sa[2 * yl] + sa[idx2];
    // loss = -ln(true alpha) = (K - log2(ahat_sum)) * ln2
    double loss = ((double)K - log2(s)) * LN2D;
    losses[b] = (float)loss;
  }
}

// Kernel 3: zero_infinity + mean over B.
__global__ __launch_bounds__(64) void k_final(const float* __restrict__ losses,
                                              float* __restrict__ out)
{
  int tid = threadIdx.x;
  float v = (tid < Bc) ? losses[tid] : 0.f;
  if (!(v < 1e29f)) v = 0.f;  // inf/nan -> 0 (zero_infinity)
#pragma unroll
  for (int off = 32; off; off >>= 1) v += __shfl_xor(v, off);
  if (tid == 0) out[0] = v / (float)Bc;
}

extern "C" void kernel_launch(void* const* d_in, const int* in_sizes, int n_in,
                              void* d_out, int out_size, void* d_ws, size_t ws_size,
                              hipStream_t stream) {
  const float* x = (const float*)d_in[0];      // [B,T,V] f32
  const int* y = (const int*)d_in[1];          // [B,S]
  const int* f_len = (const int*)d_in[2];      // [B]
  const int* y_len = (const int*)d_in[3];      // [B]
  float* out = (float*)d_out;                  // scalar f32
  float* lp = (float*)d_ws;                    // [B,T,256] f32 = 16.38 MB
  float* losses = lp + (size_t)Bc * Tc * Lpad; // [B]

  k_prob_gather<<<dim3(Bc * Tc), dim3(256), 0, stream>>>(x, y, lp);
  k_ctc_dp<<<dim3(Bc), dim3(64), 0, stream>>>(lp, y, f_len, y_len, losses);
  k_final<<<dim3(1), dim3(64), 0, stream>>>(losses, out);
}

// Round 7
// 133.359 us; speedup vs baseline: 2.3951x; 1.4967x over previous
//
#include <hip/hip_runtime.h>
#include <hip/hip_bf16.h>

#define LN2D 0.6931471805599453

constexpr int Bc = 16, Tc = 1000, Vc = 4096, Sc = 100;
constexpr int Lpad = 256;  // padded extended-label length (L = 2*S+1 = 201)

// Kernel 1: per (b,t) softmax over V, gather the 201 extended-label probs
// (LINEAR domain, f32) into lp[b][t][0..255] (s>200 -> 0). (round-6, PASSED)
__global__ __launch_bounds__(256) void k_prob_gather(
    const float* __restrict__ x, const int* __restrict__ y,
    float* __restrict__ lp)
{
  int bt = blockIdx.x;  // b*T + t
  int b = bt / Tc;
  int tid = threadIdx.x;
  const float4* row4 = (const float4*)(x + (size_t)bt * Vc);
  __shared__ float sh[Vc];
  __shared__ float red[8];
  float4* sh4 = (float4*)sh;
  float4 v[4];
  float mx = -3.4e38f;
#pragma unroll
  for (int k = 0; k < 4; ++k) {
    v[k] = row4[k * 256 + tid];
    sh4[k * 256 + tid] = v[k];
    mx = fmaxf(mx, fmaxf(fmaxf(v[k].x, v[k].y), fmaxf(v[k].z, v[k].w)));
  }
#pragma unroll
  for (int off = 32; off; off >>= 1) mx = fmaxf(mx, __shfl_xor(mx, off));
  if ((tid & 63) == 0) red[tid >> 6] = mx;
  __syncthreads();
  mx = fmaxf(fmaxf(red[0], red[1]), fmaxf(red[2], red[3]));
  float s = 0.f;
#pragma unroll
  for (int k = 0; k < 4; ++k) {
    s += __expf(v[k].x - mx) + __expf(v[k].y - mx) +
         __expf(v[k].z - mx) + __expf(v[k].w - mx);
  }
#pragma unroll
  for (int off = 32; off; off >>= 1) s += __shfl_xor(s, off);
  if ((tid & 63) == 0) red[4 + (tid >> 6)] = s;
  __syncthreads();
  s = (red[4] + red[5]) + (red[6] + red[7]);
  float lse = mx + __logf(s);
  float p;
  if (tid <= 200) {
    int lab = (tid & 1) ? y[b * Sc + (tid >> 1)] : 0;  // z[s]: blank at even s
    p = __expf(sh[lab] - lse);
  } else {
    p = 0.f;  // dead states
  }
  lp[(size_t)bt * Lpad + tid] = p;
}

// Kernel 2: scaled-forward CTC DP, f64 alphas (round-6 numerics, PASSED),
// restructured: (a) shfl_up of n3 issued at TOP of each step, result consumed
// LATE in the NEXT step -> ~120cy ds_bpermute latency amortized over 2 steps;
// (b) exact 2^{-e} global rescale every 16 steps (was 8). RESCALE also scales
// the in-flight pipelined value uc (pure pow2 mul, exact).
__global__ __launch_bounds__(64) void k_ctc_dp(
    const float* __restrict__ lp, const int* __restrict__ y,
    const int* __restrict__ f_len, const int* __restrict__ y_len,
    float* __restrict__ losses)
{
  int b = blockIdx.x;
  int lane = threadIdx.x;
  const float4* lpp = (const float4*)(lp + (size_t)b * Tc * Lpad);
  int F = f_len[b];
  const int* yb = y + b * Sc;
  int i0 = 2 * lane, i1i = 2 * lane + 1;
  int y_m1 = (i0 >= 1 && i0 - 1 < Sc) ? yb[i0 - 1] : -1;
  int y_0  = (i0 < Sc) ? yb[i0] : -2;
  int y_1  = (i1i < Sc) ? yb[i1i] : -3;
  bool allow1 = (y_0 != y_m1);
  bool allow3 = (y_1 != y_0);
  int K = 0;  // true alpha = ahat * 2^{-K}

  // init t=0
  float4 r0 = lpp[lane];
  double a0 = (lane == 0) ? (double)r0.x : 0.0;
  double a1 = (lane == 0) ? (double)r0.y : 0.0;
  double a2 = 0.0, a3 = 0.0;
  double uc = 0.0;  // pipelined shfl_up(a3) result; a3(t=0)==0 in all lanes

#define LOADK(BUF, T)                                                          \
  {                                                                            \
    int tt = (T); tt = tt < Tc ? tt : (Tc - 1);                                \
    BUF = lpp[(size_t)tt * 64 + lane];                                         \
  }

  // One DP step: issue next shuffle early, consume previous one late.
#define SP(BUF, TNEXT)                                                         \
  {                                                                            \
    float4 c = BUF; LOADK(BUF, TNEXT);                                         \
    double n3 = (a3 + a2 + (allow3 ? a1 : 0.0)) * (double)c.w;                 \
    double un = __shfl_up(n3, 1); /* for NEXT step */                          \
    double n2 = (a2 + a1) * (double)c.z;                                       \
    double u = (lane == 0) ? 0.0 : uc; /* previous step's shuffle */           \
    double n0 = (a0 + u) * (double)c.x;                                        \
    double n1 = (a1 + a0 + (allow1 ? u : 0.0)) * (double)c.y;                  \
    a0 = n0; a1 = n1; a2 = n2; a3 = n3; uc = un;                               \
  }
#define SPN(BUF)                                                               \
  {                                                                            \
    float4 c = BUF;                                                            \
    double n3 = (a3 + a2 + (allow3 ? a1 : 0.0)) * (double)c.w;                 \
    double un = __shfl_up(n3, 1);                                              \
    double n2 = (a2 + a1) * (double)c.z;                                       \
    double u = (lane == 0) ? 0.0 : uc;                                         \
    double n0 = (a0 + u) * (double)c.x;                                        \
    double n1 = (a1 + a0 + (allow1 ? u : 0.0)) * (double)c.y;                  \
    a0 = n0; a1 = n1; a2 = n2; a3 = n3; uc = un;                               \
  }

  // Exact global power-of-2 rescale (also scales in-flight uc).
#define RESCALE                                                                \
  {                                                                            \
    int _h = max(max(__double2hiint(a0), __double2hiint(a1)),                  \
                 max(__double2hiint(a2), __double2hiint(a3)));                 \
    _h = max(_h, __shfl_xor(_h, 1));                                           \
    _h = max(_h, __shfl_xor(_h, 2));                                           \
    _h = max(_h, __shfl_xor(_h, 4));                                           \
    _h = max(_h, __shfl_xor(_h, 8));                                           \
    _h = max(_h, __shfl_xor(_h, 16));                                          \
    _h = max(_h, __shfl_xor(_h, 32));                                          \
    int _e = (_h >> 20) - 1023;                                                \
    double _sc = __hiloint2double((1023 - _e) << 20, 0); /* exact 2^{-e} */    \
    a0 *= _sc; a1 *= _sc; a2 *= _sc; a3 *= _sc; uc *= _sc;                     \
    K -= _e;                                                                   \
  }

  float4 buf0, buf1, buf2, buf3, buf4, buf5, buf6, buf7;
  LOADK(buf0, 1); LOADK(buf1, 2); LOADK(buf2, 3); LOADK(buf3, 4);
  LOADK(buf4, 5); LOADK(buf5, 6); LOADK(buf6, 7); LOADK(buf7, 8);

  int t = 1;
  for (; t + 16 <= F; t += 16) {
    SP(buf0, t + 8);  SP(buf1, t + 9);  SP(buf2, t + 10); SP(buf3, t + 11);
    SP(buf4, t + 12); SP(buf5, t + 13); SP(buf6, t + 14); SP(buf7, t + 15);
    SP(buf0, t + 16); SP(buf1, t + 17); SP(buf2, t + 18); SP(buf3, t + 19);
    SP(buf4, t + 20); SP(buf5, t + 21); SP(buf6, t + 22); SP(buf7, t + 23);
    RESCALE;
  }
  if (t + 8 <= F) {
    SP(buf0, t + 8);  SP(buf1, t + 9);  SP(buf2, t + 10); SP(buf3, t + 11);
    SP(buf4, t + 12); SP(buf5, t + 13); SP(buf6, t + 14); SP(buf7, t + 15);
    t += 8;
    RESCALE;
  }
  // remaining <8 steps: ring already holds rows t..t+6
  if (t < F) { SPN(buf0); ++t; }
  if (t < F) { SPN(buf1); ++t; }
  if (t < F) { SPN(buf2); ++t; }
  if (t < F) { SPN(buf3); ++t; }
  if (t < F) { SPN(buf4); ++t; }
  if (t < F) { SPN(buf5); ++t; }
  if (t < F) { SPN(buf6); ++t; }

  __shared__ double sa[256];
  sa[4 * lane + 0] = a0;
  sa[4 * lane + 1] = a1;
  sa[4 * lane + 2] = a2;
  sa[4 * lane + 3] = a3;
  __syncthreads();
  if (lane == 0) {
    int yl = y_len[b];
    int idx2 = (2 * yl - 1 > 0) ? (2 * yl - 1) : 0;
    double s = sa[2 * yl] + sa[idx2];
    double loss = ((double)K - log2(s)) * LN2D;  // -ln(alpha_true)
    losses[b] = (float)loss;
  }
}

// Kernel 3: zero_infinity + mean over B.
__global__ __launch_bounds__(64) void k_final(const float* __restrict__ losses,
                                              float* __restrict__ out)
{
  int tid = threadIdx.x;
  float v = (tid < Bc) ? losses[tid] : 0.f;
  if (!(v < 1e29f)) v = 0.f;  // inf/nan -> 0 (zero_infinity)
#pragma unroll
  for (int off = 32; off; off >>= 1) v += __shfl_xor(v, off);
  if (tid == 0) out[0] = v / (float)Bc;
}

extern "C" void kernel_launch(void* const* d_in, const int* in_sizes, int n_in,
                              void* d_out, int out_size, void* d_ws, size_t ws_size,
                              hipStream_t stream) {
  const float* x = (const float*)d_in[0];      // [B,T,V] f32
  const int* y = (const int*)d_in[1];          // [B,S]
  const int* f_len = (const int*)d_in[2];      // [B]
  const int* y_len = (const int*)d_in[3];      // [B]
  float* out = (float*)d_out;                  // scalar f32
  float* lp = (float*)d_ws;                    // [B,T,256] f32 = 16.38 MB
  float* losses = lp + (size_t)Bc * Tc * Lpad; // [B]

  k_prob_gather<<<dim3(Bc * Tc), dim3(256), 0, stream>>>(x, y, lp);
  k_ctc_dp<<<dim3(Bc), dim3(64), 0, stream>>>(lp, y, f_len, y_len, losses);
  k_final<<<dim3(1), dim3(64), 0, stream>>>(losses, out);
}

// Round 8
// 133.037 us; speedup vs baseline: 2.4009x; 1.0024x over previous
//
#include <hip/hip_runtime.h>
#include <hip/hip_bf16.h>

#define LN2D 0.6931471805599453

constexpr int Bc = 16, Tc = 1000, Vc = 4096, Sc = 100;
constexpr int Lpad = 256;  // padded extended-label length (L = 2*S+1 = 201)

// Kernel 1: per (b,t) softmax over V, gather the 201 extended-label probs
// (LINEAR domain, f32) into lp[b][t][0..255] (s>200 -> 0). (rounds 6/7 PASSED)
__global__ __launch_bounds__(256) void k_prob_gather(
    const float* __restrict__ x, const int* __restrict__ y,
    float* __restrict__ lp)
{
  int bt = blockIdx.x;  // b*T + t
  int b = bt / Tc;
  int tid = threadIdx.x;
  const float4* row4 = (const float4*)(x + (size_t)bt * Vc);
  __shared__ float sh[Vc];
  __shared__ float red[8];
  float4* sh4 = (float4*)sh;
  float4 v[4];
  float mx = -3.4e38f;
#pragma unroll
  for (int k = 0; k < 4; ++k) {
    v[k] = row4[k * 256 + tid];
    sh4[k * 256 + tid] = v[k];
    mx = fmaxf(mx, fmaxf(fmaxf(v[k].x, v[k].y), fmaxf(v[k].z, v[k].w)));
  }
#pragma unroll
  for (int off = 32; off; off >>= 1) mx = fmaxf(mx, __shfl_xor(mx, off));
  if ((tid & 63) == 0) red[tid >> 6] = mx;
  __syncthreads();
  mx = fmaxf(fmaxf(red[0], red[1]), fmaxf(red[2], red[3]));
  float s = 0.f;
#pragma unroll
  for (int k = 0; k < 4; ++k) {
    s += __expf(v[k].x - mx) + __expf(v[k].y - mx) +
         __expf(v[k].z - mx) + __expf(v[k].w - mx);
  }
#pragma unroll
  for (int off = 32; off; off >>= 1) s += __shfl_xor(s, off);
  if ((tid & 63) == 0) red[4 + (tid >> 6)] = s;
  __syncthreads();
  s = (red[4] + red[5]) + (red[6] + red[7]);
  float lse = mx + __logf(s);
  float p;
  if (tid <= 200) {
    int lab = (tid & 1) ? y[b * Sc + (tid >> 1)] : 0;  // z[s]: blank at even s
    p = __expf(sh[lab] - lse);
  } else {
    p = 0.f;  // dead states
  }
  lp[(size_t)bt * Lpad + tid] = p;
}

// Kernel 2: scaled-forward CTC DP, f64 alphas (round-6/7 numerics, PASSED).
// Lag-2 cross-lane: shuffle sigma = a3+a2+allow3*a1 (the pre-mul sum) instead
// of a3; consumer applies the final multiply by the neighbor's prob itself:
//   u(t) = a3'(t-1) = sigma'(t-2) * p_{4L-1}(t-1)
// sigma issued at end of step t-2, consumed at t (2 iterations of slack for
// the ~150cy ds_bpermute latency). Neighbor prob via shfl_up(prev row .w),
// also issued 2 steps early from the ring. A/B slot alternation (no rotation
// copies). Rescale max-reduce spread across the 16-step window; exact 2^-e
// apply touches only local regs; in-flight sigmas get the scale folded into
// their consumption (the two "* scp" steps).
__global__ __launch_bounds__(64) void k_ctc_dp(
    const float* __restrict__ lp, const int* __restrict__ y,
    const int* __restrict__ f_len, const int* __restrict__ y_len,
    float* __restrict__ losses)
{
  int b = blockIdx.x;
  int lane = threadIdx.x;
  const float4* lpp = (const float4*)(lp + (size_t)b * Tc * Lpad);
  int F = f_len[b];
  const int* yb = y + b * Sc;
  int i0 = 2 * lane, i1i = 2 * lane + 1;
  int y_m1 = (i0 >= 1 && i0 - 1 < Sc) ? yb[i0 - 1] : -1;
  int y_0  = (i0 < Sc) ? yb[i0] : -2;
  int y_1  = (i1i < Sc) ? yb[i1i] : -3;
  bool allow1 = (y_0 != y_m1);
  bool allow3 = (y_1 != y_0);
  int K = 0;  // true alpha = ahat * 2^{-K}

  // init t=0
  float4 r0 = lpp[lane];
  double a0 = (lane == 0) ? (double)r0.x : 0.0;
  double a1 = (lane == 0) ? (double)r0.y : 0.0;
  double a2 = 0.0, a3 = 0.0;
  double sig = a3 + a2 + (allow3 ? a1 : 0.0);  // sigma(0); own n3 pre-sum

#define LOADK(BUF, T)                                                         \
  {                                                                           \
    int tt = (T); tt = tt < Tc ? tt : (Tc - 1);                               \
    BUF = lpp[(size_t)tt * 64 + lane];                                        \
  }

  float4 buf0, buf1, buf2, buf3, buf4, buf5, buf6, buf7;
  LOADK(buf0, 1); LOADK(buf1, 2); LOADK(buf2, 3); LOADK(buf3, 4);
  LOADK(buf4, 5); LOADK(buf5, 6); LOADK(buf6, 7); LOADK(buf7, 8);

  // In-flight shuffle slots. Step parity A/B: step 1 consumes A, step 2 B, ...
  double sigA = 0.0;                 // u for step 1 is 0 (a3(0)==0 everywhere)
  double sigB = __shfl_up(sig, 1);   // sigma'(0), consumed at step 2
  float  wA = 0.f;                   // unused at step 1
  float  wB = __shfl_up(buf0.w, 1);  // row-1 .w', consumed at step 2

  // One DP step. SLOT in {A,B}: consume sigSLOT/wSLOT (issued 2 steps ago),
  // re-issue into the same slot. UX: optional "* scp" post-rescale fixup.
#define SPG(B, NB, TN, SIGS, WS, UX)                                          \
  {                                                                           \
    float4 c = B; LOADK(B, TN);                                               \
    double u = (lane == 0) ? 0.0 : SIGS * (double)WS;                         \
    u = u UX;                                                                 \
    double n0 = (a0 + u) * (double)c.x;                                       \
    double n1 = (a1 + a0 + (allow1 ? u : 0.0)) * (double)c.y;                 \
    double n2 = (a2 + a1) * (double)c.z;                                      \
    double n3 = sig * (double)c.w;                                            \
    double sg = n3 + n2 + (allow3 ? n1 : 0.0);                                \
    SIGS = __shfl_up(sg, 1);                                                  \
    WS = __shfl_up(NB.w, 1);                                                  \
    a0 = n0; a1 = n1; a2 = n2; a3 = n3; sig = sg;                             \
  }
#define SPNG(B, NB, SIGS, WS)                                                 \
  {                                                                           \
    float4 c = B;                                                             \
    double u = (lane == 0) ? 0.0 : SIGS * (double)WS;                         \
    double n0 = (a0 + u) * (double)c.x;                                      \
    double n1 = (a1 + a0 + (allow1 ? u : 0.0)) * (double)c.y;                \
    double n2 = (a2 + a1) * (double)c.z;                                     \
    double n3 = sig * (double)c.w;                                           \
    double sg = n3 + n2 + (allow3 ? n1 : 0.0);                               \
    SIGS = __shfl_up(sg, 1);                                                 \
    WS = __shfl_up(NB.w, 1);                                                 \
    a0 = n0; a1 = n1; a2 = n2; a3 = n3; sig = sg;                            \
  }
#define SPA(B, NB, TN)      SPG(B, NB, TN, sigA, wA, )
#define SPB(B, NB, TN)      SPG(B, NB, TN, sigB, wB, )
#define SPA_SC(B, NB, TN)   SPG(B, NB, TN, sigA, wA, * scp)
#define SPB_SC(B, NB, TN)   SPG(B, NB, TN, sigB, wB, * scp)
#define SPNA(B, NB)         SPNG(B, NB, sigA, wA)
#define SPNB(B, NB)         SPNG(B, NB, sigB, wB)

  int t = 1;
  int h, xi;
  for (; t + 16 <= F; t += 16) {
    // s0..s15 = steps t..t+15; reduce stages interleaved (lag-2 each)
    SPA(buf0, buf1, t + 8);
    h = max(max(__double2hiint(a0), __double2hiint(a1)),
            max(__double2hiint(a2), __double2hiint(a3)));
    SPB(buf1, buf2, t + 9);
    xi = __shfl_xor(h, 1);
    SPA(buf2, buf3, t + 10);
    SPB(buf3, buf4, t + 11);
    h = max(h, xi); xi = __shfl_xor(h, 2);
    SPA(buf4, buf5, t + 12);
    SPB(buf5, buf6, t + 13);
    h = max(h, xi); xi = __shfl_xor(h, 4);
    SPA(buf6, buf7, t + 14);
    SPB(buf7, buf0, t + 15);
    h = max(h, xi); xi = __shfl_xor(h, 8);
    SPA(buf0, buf1, t + 16);
    SPB(buf1, buf2, t + 17);
    h = max(h, xi); xi = __shfl_xor(h, 16);
    SPA(buf2, buf3, t + 18);
    SPB(buf3, buf4, t + 19);
    h = max(h, xi); xi = __shfl_xor(h, 32);
    SPA(buf4, buf5, t + 20);
    SPB(buf5, buf6, t + 21);
    // APPLY: exact 2^{-e} (biased +256 to center the f64 window); local regs
    // only — the two in-flight sigmas get the scale at consumption below.
    h = max(h, xi);
    {
      int e = (h >> 20) - 1279;  // (h>>20)-1023-256
      double scp = __hiloint2double((1023 - e) << 20, 0);
      a0 *= scp; a1 *= scp; a2 *= scp; a3 *= scp; sig *= scp;
      K -= e;
      SPA_SC(buf6, buf7, t + 22);
      SPB_SC(buf7, buf0, t + 23);
    }
  }
  // up to 15 steps remain; ring holds rows t..t+7
  if (t + 8 <= F) {
    SPA(buf0, buf1, t + 8);  SPB(buf1, buf2, t + 9);
    SPA(buf2, buf3, t + 10); SPB(buf3, buf4, t + 11);
    SPA(buf4, buf5, t + 12); SPB(buf5, buf6, t + 13);
    SPA(buf6, buf7, t + 14); SPB(buf7, buf0, t + 15);
    t += 8;
  }
  if (t < F) { SPNA(buf0, buf1); ++t; }
  if (t < F) { SPNB(buf1, buf2); ++t; }
  if (t < F) { SPNA(buf2, buf3); ++t; }
  if (t < F) { SPNB(buf3, buf4); ++t; }
  if (t < F) { SPNA(buf4, buf5); ++t; }
  if (t < F) { SPNB(buf5, buf6); ++t; }
  if (t < F) { SPNA(buf6, buf7); ++t; }

  __shared__ double sa[256];
  sa[4 * lane + 0] = a0;
  sa[4 * lane + 1] = a1;
  sa[4 * lane + 2] = a2;
  sa[4 * lane + 3] = a3;
  __syncthreads();
  if (lane == 0) {
    int yl = y_len[b];
    int idx2 = (2 * yl - 1 > 0) ? (2 * yl - 1) : 0;
    double s = sa[2 * yl] + sa[idx2];
    double loss = ((double)K - log2(s)) * LN2D;  // -ln(alpha_true)
    losses[b] = (float)loss;
  }
}

// Kernel 3: zero_infinity + mean over B.
__global__ __launch_bounds__(64) void k_final(const float* __restrict__ losses,
                                              float* __restrict__ out)
{
  int tid = threadIdx.x;
  float v = (tid < Bc) ? losses[tid] : 0.f;
  if (!(v < 1e29f)) v = 0.f;  // inf/nan -> 0 (zero_infinity)
#pragma unroll
  for (int off = 32; off; off >>= 1) v += __shfl_xor(v, off);
  if (tid == 0) out[0] = v / (float)Bc;
}

extern "C" void kernel_launch(void* const* d_in, const int* in_sizes, int n_in,
                              void* d_out, int out_size, void* d_ws, size_t ws_size,
                              hipStream_t stream) {
  const float* x = (const float*)d_in[0];      // [B,T,V] f32
  const int* y = (const int*)d_in[1];          // [B,S]
  const int* f_len = (const int*)d_in[2];      // [B]
  const int* y_len = (const int*)d_in[3];      // [B]
  float* out = (float*)d_out;                  // scalar f32
  float* lp = (float*)d_ws;                    // [B,T,256] f32 = 16.38 MB
  float* losses = lp + (size_t)Bc * Tc * Lpad; // [B]

  k_prob_gather<<<dim3(Bc * Tc), dim3(256), 0, stream>>>(x, y, lp);
  k_ctc_dp<<<dim3(Bc), dim3(64), 0, stream>>>(lp, y, f_len, y_len, losses);
  k_final<<<dim3(1), dim3(64), 0, stream>>>(losses, out);
}

// Round 9
// 130.267 us; speedup vs baseline: 2.4520x; 1.0213x over previous
//
#include <hip/hip_runtime.h>
#include <hip/hip_bf16.h>

#define LN2D 0.6931471805599453

constexpr int Bc = 16, Tc = 1000, Vc = 4096, Sc = 100;
constexpr int Lpad = 256;  // padded extended-label length (L = 2*S+1 = 201)

// Kernel 1: per (b,t) softmax over V, gather the 201 extended-label probs
// (LINEAR domain, f32) into lp[b][t][0..255] (s>200 -> 0). (rounds 6-8 PASSED)
__global__ __launch_bounds__(256) void k_prob_gather(
    const float* __restrict__ x, const int* __restrict__ y,
    float* __restrict__ lp)
{
  int bt = blockIdx.x;  // b*T + t
  int b = bt / Tc;
  int tid = threadIdx.x;
  const float4* row4 = (const float4*)(x + (size_t)bt * Vc);
  __shared__ float sh[Vc];
  __shared__ float red[8];
  float4* sh4 = (float4*)sh;
  float4 v[4];
  float mx = -3.4e38f;
#pragma unroll
  for (int k = 0; k < 4; ++k) {
    v[k] = row4[k * 256 + tid];
    sh4[k * 256 + tid] = v[k];
    mx = fmaxf(mx, fmaxf(fmaxf(v[k].x, v[k].y), fmaxf(v[k].z, v[k].w)));
  }
#pragma unroll
  for (int off = 32; off; off >>= 1) mx = fmaxf(mx, __shfl_xor(mx, off));
  if ((tid & 63) == 0) red[tid >> 6] = mx;
  __syncthreads();
  mx = fmaxf(fmaxf(red[0], red[1]), fmaxf(red[2], red[3]));
  float s = 0.f;
#pragma unroll
  for (int k = 0; k < 4; ++k) {
    s += __expf(v[k].x - mx) + __expf(v[k].y - mx) +
         __expf(v[k].z - mx) + __expf(v[k].w - mx);
  }
#pragma unroll
  for (int off = 32; off; off >>= 1) s += __shfl_xor(s, off);
  if ((tid & 63) == 0) red[4 + (tid >> 6)] = s;
  __syncthreads();
  s = (red[4] + red[5]) + (red[6] + red[7]);
  float lse = mx + __logf(s);
  float p;
  if (tid <= 200) {
    int lab = (tid & 1) ? y[b * Sc + (tid >> 1)] : 0;  // z[s]: blank at even s
    p = __expf(sh[lab] - lse);
  } else {
    p = 0.f;  // dead states
  }
  lp[(size_t)bt * Lpad + tid] = p;
}

// Whole-wave lane-1 shift via DPP wave_shr:1 (ctrl 0x138) — VALU pipe, no
// lgkm counter. Lane 0 gets old=0 (bound_ctrl=false -> invalid lanes read old).
__device__ __forceinline__ double dpp_wshr1_f64(double x) {
  int lo = __double2loint(x), hi = __double2hiint(x);
  lo = __builtin_amdgcn_update_dpp(0, lo, 0x138, 0xF, 0xF, false);
  hi = __builtin_amdgcn_update_dpp(0, hi, 0x138, 0xF, 0xF, false);
  return __hiloint2double(hi, lo);
}
__device__ __forceinline__ float dpp_wshr1_f32(float x) {
  int v = __float_as_int(x);
  v = __builtin_amdgcn_update_dpp(0, v, 0x138, 0xF, 0xF, false);
  return __int_as_float(v);
}

// Kernel 2: scaled-forward CTC DP, f64 alphas (rounds 6-8 numerics, PASSED).
// Identical structure to round 8; ONLY change: the per-step cross-lane
// transfers (sigma f64, w f32) use DPP wave_shr:1 instead of __shfl_up
// (ds_bpermute). Model: every shfl consume was a full lgkmcnt(0) drain
// (~120-150cy) -> R6/7/8 step times 377/218/218cy. DPP removes all in-loop
// lgkm ops; rescale's shfl_xor drains become ~free (2-step-old, completed).
__global__ __launch_bounds__(64) void k_ctc_dp(
    const float* __restrict__ lp, const int* __restrict__ y,
    const int* __restrict__ f_len, const int* __restrict__ y_len,
    float* __restrict__ losses)
{
  int b = blockIdx.x;
  int lane = threadIdx.x;
  const float4* lpp = (const float4*)(lp + (size_t)b * Tc * Lpad);
  int F = f_len[b];
  const int* yb = y + b * Sc;
  int i0 = 2 * lane, i1i = 2 * lane + 1;
  int y_m1 = (i0 >= 1 && i0 - 1 < Sc) ? yb[i0 - 1] : -1;
  int y_0  = (i0 < Sc) ? yb[i0] : -2;
  int y_1  = (i1i < Sc) ? yb[i1i] : -3;
  bool allow1 = (y_0 != y_m1);
  bool allow3 = (y_1 != y_0);
  int K = 0;  // true alpha = ahat * 2^{-K}

  // init t=0
  float4 r0 = lpp[lane];
  double a0 = (lane == 0) ? (double)r0.x : 0.0;
  double a1 = (lane == 0) ? (double)r0.y : 0.0;
  double a2 = 0.0, a3 = 0.0;
  double sig = a3 + a2 + (allow3 ? a1 : 0.0);  // sigma(0); own n3 pre-sum

#define LOADK(BUF, T)                                                         \
  {                                                                           \
    int tt = (T); tt = tt < Tc ? tt : (Tc - 1);                               \
    BUF = lpp[(size_t)tt * 64 + lane];                                        \
  }

  float4 buf0, buf1, buf2, buf3, buf4, buf5, buf6, buf7;
  LOADK(buf0, 1); LOADK(buf1, 2); LOADK(buf2, 3); LOADK(buf3, 4);
  LOADK(buf4, 5); LOADK(buf5, 6); LOADK(buf6, 7); LOADK(buf7, 8);

  // In-flight cross-lane slots (A/B parity), now DPP (instant, VALU).
  double sigA = 0.0;                     // u for step 1 is 0 (a3(0)==0)
  double sigB = dpp_wshr1_f64(sig);      // sigma'(0), consumed at step 2
  float  wA = 0.f;                       // unused at step 1
  float  wB = dpp_wshr1_f32(buf0.w);     // row-1 .w', consumed at step 2

  // One DP step. SLOT in {A,B}: consume sigSLOT/wSLOT (issued 2 steps ago),
  // re-issue into the same slot. UX: optional "* scp" post-rescale fixup.
#define SPG(B, NB, TN, SIGS, WS, UX)                                          \
  {                                                                           \
    float4 c = B; LOADK(B, TN);                                               \
    double u = (lane == 0) ? 0.0 : SIGS * (double)WS;                         \
    u = u UX;                                                                 \
    double n0 = (a0 + u) * (double)c.x;                                       \
    double n1 = (a1 + a0 + (allow1 ? u : 0.0)) * (double)c.y;                 \
    double n2 = (a2 + a1) * (double)c.z;                                      \
    double n3 = sig * (double)c.w;                                            \
    double sg = n3 + n2 + (allow3 ? n1 : 0.0);                                \
    SIGS = dpp_wshr1_f64(sg);                                                 \
    WS = dpp_wshr1_f32(NB.w);                                                 \
    a0 = n0; a1 = n1; a2 = n2; a3 = n3; sig = sg;                             \
  }
#define SPNG(B, NB, SIGS, WS)                                                 \
  {                                                                           \
    float4 c = B;                                                             \
    double u = (lane == 0) ? 0.0 : SIGS * (double)WS;                         \
    double n0 = (a0 + u) * (double)c.x;                                       \
    double n1 = (a1 + a0 + (allow1 ? u : 0.0)) * (double)c.y;                 \
    double n2 = (a2 + a1) * (double)c.z;                                      \
    double n3 = sig * (double)c.w;                                            \
    double sg = n3 + n2 + (allow3 ? n1 : 0.0);                                \
    SIGS = dpp_wshr1_f64(sg);                                                 \
    WS = dpp_wshr1_f32(NB.w);                                                 \
    a0 = n0; a1 = n1; a2 = n2; a3 = n3; sig = sg;                             \
  }
#define SPA(B, NB, TN)      SPG(B, NB, TN, sigA, wA, )
#define SPB(B, NB, TN)      SPG(B, NB, TN, sigB, wB, )
#define SPA_SC(B, NB, TN)   SPG(B, NB, TN, sigA, wA, * scp)
#define SPB_SC(B, NB, TN)   SPG(B, NB, TN, sigB, wB, * scp)
#define SPNA(B, NB)         SPNG(B, NB, sigA, wA)
#define SPNB(B, NB)         SPNG(B, NB, sigB, wB)

  int t = 1;
  int h, xi;
  for (; t + 16 <= F; t += 16) {
    // steps t..t+15; rescale max-reduce stages interleaved (lag-2 each)
    SPA(buf0, buf1, t + 8);
    h = max(max(__double2hiint(a0), __double2hiint(a1)),
            max(__double2hiint(a2), __double2hiint(a3)));
    SPB(buf1, buf2, t + 9);
    xi = __shfl_xor(h, 1);
    SPA(buf2, buf3, t + 10);
    SPB(buf3, buf4, t + 11);
    h = max(h, xi); xi = __shfl_xor(h, 2);
    SPA(buf4, buf5, t + 12);
    SPB(buf5, buf6, t + 13);
    h = max(h, xi); xi = __shfl_xor(h, 4);
    SPA(buf6, buf7, t + 14);
    SPB(buf7, buf0, t + 15);
    h = max(h, xi); xi = __shfl_xor(h, 8);
    SPA(buf0, buf1, t + 16);
    SPB(buf1, buf2, t + 17);
    h = max(h, xi); xi = __shfl_xor(h, 16);
    SPA(buf2, buf3, t + 18);
    SPB(buf3, buf4, t + 19);
    h = max(h, xi); xi = __shfl_xor(h, 32);
    SPA(buf4, buf5, t + 20);
    SPB(buf5, buf6, t + 21);
    // APPLY: exact 2^{-e} (biased +256 to center the f64 window); in-flight
    // sigmas get the scale folded into their consumption below.
    h = max(h, xi);
    {
      int e = (h >> 20) - 1279;  // (h>>20)-1023-256
      double scp = __hiloint2double((1023 - e) << 20, 0);
      a0 *= scp; a1 *= scp; a2 *= scp; a3 *= scp; sig *= scp;
      K -= e;
      SPA_SC(buf6, buf7, t + 22);
      SPB_SC(buf7, buf0, t + 23);
    }
  }
  // up to 15 steps remain; ring holds rows t..t+7
  if (t + 8 <= F) {
    SPA(buf0, buf1, t + 8);  SPB(buf1, buf2, t + 9);
    SPA(buf2, buf3, t + 10); SPB(buf3, buf4, t + 11);
    SPA(buf4, buf5, t + 12); SPB(buf5, buf6, t + 13);
    SPA(buf6, buf7, t + 14); SPB(buf7, buf0, t + 15);
    t += 8;
  }
  if (t < F) { SPNA(buf0, buf1); ++t; }
  if (t < F) { SPNB(buf1, buf2); ++t; }
  if (t < F) { SPNA(buf2, buf3); ++t; }
  if (t < F) { SPNB(buf3, buf4); ++t; }
  if (t < F) { SPNA(buf4, buf5); ++t; }
  if (t < F) { SPNB(buf5, buf6); ++t; }
  if (t < F) { SPNA(buf6, buf7); ++t; }

  __shared__ double sa[256];
  sa[4 * lane + 0] = a0;
  sa[4 * lane + 1] = a1;
  sa[4 * lane + 2] = a2;
  sa[4 * lane + 3] = a3;
  __syncthreads();
  if (lane == 0) {
    int yl = y_len[b];
    int idx2 = (2 * yl - 1 > 0) ? (2 * yl - 1) : 0;
    double s = sa[2 * yl] + sa[idx2];
    double loss = ((double)K - log2(s)) * LN2D;  // -ln(alpha_true)
    losses[b] = (float)loss;
  }
}

// Kernel 3: zero_infinity + mean over B.
__global__ __launch_bounds__(64) void k_final(const float* __restrict__ losses,
                                              float* __restrict__ out)
{
  int tid = threadIdx.x;
  float v = (tid < Bc) ? losses[tid] : 0.f;
  if (!(v < 1e29f)) v = 0.f;  // inf/nan -> 0 (zero_infinity)
#pragma unroll
  for (int off = 32; off; off >>= 1) v += __shfl_xor(v, off);
  if (tid == 0) out[0] = v / (float)Bc;
}

extern "C" void kernel_launch(void* const* d_in, const int* in_sizes, int n_in,
                              void* d_out, int out_size, void* d_ws, size_t ws_size,
                              hipStream_t stream) {
  const float* x = (const float*)d_in[0];      // [B,T,V] f32
  const int* y = (const int*)d_in[1];          // [B,S]
  const int* f_len = (const int*)d_in[2];      // [B]
  const int* y_len = (const int*)d_in[3];      // [B]
  float* out = (float*)d_out;                  // scalar f32
  float* lp = (float*)d_ws;                    // [B,T,256] f32 = 16.38 MB
  float* losses = lp + (size_t)Bc * Tc * Lpad; // [B]

  k_prob_gather<<<dim3(Bc * Tc), dim3(256), 0, stream>>>(x, y, lp);
  k_ctc_dp<<<dim3(Bc), dim3(64), 0, stream>>>(lp, y, f_len, y_len, losses);
  k_final<<<dim3(1), dim3(64), 0, stream>>>(losses, out);
}

// Round 10
// 107.491 us; speedup vs baseline: 2.9715x; 1.2119x over previous
//
#include <hip/hip_runtime.h>
#include <hip/hip_bf16.h>

#define LN2D 0.6931471805599453

constexpr int Bc = 16, Tc = 1000, Vc = 4096, Sc = 100;
constexpr int TP = Tc / 2;  // 500 time-pairs; pp[b][tp][s(256)][t&1] bf16

// Kernel 1: per (b,t) softmax over V, gather the 201 extended-label probs
// (LINEAR domain) as bf16 into pp[b][t>>1][s][t&1]. Rows t>=f_len[b] are
// never consumed by the DP (skip: saves compute + write traffic).
__global__ __launch_bounds__(256) void k_prob_gather(
    const float* __restrict__ x, const int* __restrict__ y,
    const int* __restrict__ f_len, __hip_bfloat16* __restrict__ pp)
{
  int bt = blockIdx.x;  // b*T + t
  int b = bt / Tc;
  int t = bt - b * Tc;
  if (t >= f_len[b]) return;
  int tid = threadIdx.x;
  const float4* row4 = (const float4*)(x + (size_t)bt * Vc);
  __shared__ float sh[Vc];
  __shared__ float red[8];
  float4* sh4 = (float4*)sh;
  float4 v[4];
  float mx = -3.4e38f;
#pragma unroll
  for (int k = 0; k < 4; ++k) {
    v[k] = row4[k * 256 + tid];
    sh4[k * 256 + tid] = v[k];
    mx = fmaxf(mx, fmaxf(fmaxf(v[k].x, v[k].y), fmaxf(v[k].z, v[k].w)));
  }
#pragma unroll
  for (int off = 32; off; off >>= 1) mx = fmaxf(mx, __shfl_xor(mx, off));
  if ((tid & 63) == 0) red[tid >> 6] = mx;
  __syncthreads();
  mx = fmaxf(fmaxf(red[0], red[1]), fmaxf(red[2], red[3]));
  float s = 0.f;
#pragma unroll
  for (int k = 0; k < 4; ++k) {
    s += __expf(v[k].x - mx) + __expf(v[k].y - mx) +
         __expf(v[k].z - mx) + __expf(v[k].w - mx);
  }
#pragma unroll
  for (int off = 32; off; off >>= 1) s += __shfl_xor(s, off);
  if ((tid & 63) == 0) red[4 + (tid >> 6)] = s;
  __syncthreads();
  s = (red[4] + red[5]) + (red[6] + red[7]);
  float lse = mx + __logf(s);
  float p;
  if (tid <= 200) {
    int lab = (tid & 1) ? y[b * Sc + (tid >> 1)] : 0;  // z[s]: blank at even s
    p = __expf(sh[lab] - lse);
  } else {
    p = 0.f;  // dead states
  }
  pp[(size_t)b * (TP * 512) + (size_t)(t >> 1) * 512 + tid * 2 + (t & 1)] =
      __float2bfloat16(p);
}

// Whole-wave lane-1 shift via DPP wave_shr:1 (ctrl 0x138) — VALU pipe, no
// lgkm counter. Lane 0 reads old=0. (Proven in passing round 9.)
__device__ __forceinline__ double dpp_wshr1_f64(double x) {
  int lo = __double2loint(x), hi = __double2hiint(x);
  lo = __builtin_amdgcn_update_dpp(0, lo, 0x138, 0xF, 0xF, false);
  hi = __builtin_amdgcn_update_dpp(0, hi, 0x138, 0xF, 0xF, false);
  return __hiloint2double(hi, lo);
}

// Kernel 2: scaled-forward CTC DP, f64 alphas (rounds 6-9 numerics, PASSED).
// bf16 prob pairs: one uint4/lane = states 4L..4L+3 x {even,odd} timestep ->
// one load per TWO steps; 16-deep register ring = 32 steps of latency cover
// (the R7-R9 bottleneck was load service rate at depth 8, 16B/step).
// Cross-lane a3 via lag-1 DPP wave_shr (instant). Rescale: R2-proven
// row_ror rotation-reduce + 4 readlanes (no ds_bpermute anywhere in loop).
__global__ __launch_bounds__(64) void k_ctc_dp(
    const __hip_bfloat16* __restrict__ pp, const int* __restrict__ y,
    const int* __restrict__ f_len, const int* __restrict__ y_len,
    float* __restrict__ losses)
{
  int b = blockIdx.x;
  int lane = threadIdx.x;
  const uint4* pbp = (const uint4*)(pp + (size_t)b * (TP * 512));  // 64/pair
  int F = f_len[b];
  const int* yb = y + b * Sc;
  int i0 = 2 * lane, i1i = 2 * lane + 1;
  int y_m1 = (i0 >= 1 && i0 - 1 < Sc) ? yb[i0 - 1] : -1;
  int y_0  = (i0 < Sc) ? yb[i0] : -2;
  int y_1  = (i1i < Sc) ? yb[i1i] : -3;
  bool allow1 = (y_0 != y_m1);
  bool allow3 = (y_1 != y_0);
  int K = 0;  // true alpha = ahat * 2^{-K}

#define LODW(W) ((double)__int_as_float((int)((W) << 16)))
#define HIDW(W) ((double)__int_as_float((int)((W) & 0xffff0000u)))

  // init t=0 from pair 0 lo
  uint4 u0 = pbp[lane];
  double a0 = (lane == 0) ? LODW(u0.x) : 0.0;
  double a1 = (lane == 0) ? LODW(u0.y) : 0.0;
  double a2 = 0.0, a3 = 0.0;
  double un = 0.0;  // dpp_wshr1(a3 of previous step); a3(0)==0 everywhere

  // one DP step (u = neighbor a3 from previous step, via carried un)
#define SC(PX, PY, PZ, PW)                                                    \
  {                                                                           \
    double u = (lane == 0) ? 0.0 : un;                                        \
    double n0 = (a0 + u) * (PX);                                              \
    double n1 = (a1 + a0 + (allow1 ? u : 0.0)) * (PY);                        \
    double n2 = (a2 + a1) * (PZ);                                             \
    double n3 = (a3 + a2 + (allow3 ? a1 : 0.0)) * (PW);                       \
    un = dpp_wshr1_f64(n3);                                                   \
    a0 = n0; a1 = n1; a2 = n2; a3 = n3;                                       \
  }

#define LOADP(B, T)                                                           \
  {                                                                           \
    int tt = (T); tt = tt < TP ? tt : (TP - 1);                               \
    B = pbp[(size_t)tt * 64 + lane];                                          \
  }

  // pair step with prefetch
#define PAIRP(B, TN)                                                          \
  {                                                                           \
    uint4 c = B; LOADP(B, TN);                                                \
    SC(LODW(c.x), LODW(c.y), LODW(c.z), LODW(c.w));                           \
    SC(HIDW(c.x), HIDW(c.y), HIDW(c.z), HIDW(c.w));                           \
  }
  // guarded tail pair (no prefetch)
#define TPAIR(B)                                                              \
  if (2 * k < F) {                                                            \
    uint4 c = B;                                                              \
    SC(LODW(c.x), LODW(c.y), LODW(c.z), LODW(c.w));                          \
    if (2 * k + 1 < F) { SC(HIDW(c.x), HIDW(c.y), HIDW(c.z), HIDW(c.w)); }   \
    ++k;                                                                      \
  }

  // Rescale: R2-proven row_ror rotation max-reduce + 4 readlanes (uniform).
  // Exact 2^{-e}, biased +256 to center the f64 window; scales un too.
#define RORMAXI(M, CTRL)                                                      \
  {                                                                           \
    int _t = __builtin_amdgcn_update_dpp(0, (M), (CTRL), 0xF, 0xF, false);    \
    (M) = (_t > (M)) ? _t : (M);                                              \
  }
#define RESCALE                                                               \
  {                                                                           \
    int _h = max(max(__double2hiint(a0), __double2hiint(a1)),                 \
                 max(__double2hiint(a2), __double2hiint(a3)));                \
    RORMAXI(_h, 0x121); RORMAXI(_h, 0x122);                                   \
    RORMAXI(_h, 0x124); RORMAXI(_h, 0x128);                                   \
    int _g = max(max(__builtin_amdgcn_readlane(_h, 0),                        \
                     __builtin_amdgcn_readlane(_h, 16)),                      \
                 max(__builtin_amdgcn_readlane(_h, 32),                       \
                     __builtin_amdgcn_readlane(_h, 48)));                     \
    int _e = (_g >> 20) - 1279; /* true_exp - 256 */                          \
    double _sc = __hiloint2double((1023 - _e) << 20, 0); /* exact 2^{-e} */   \
    a0 *= _sc; a1 *= _sc; a2 *= _sc; a3 *= _sc; un *= _sc;                    \
    K -= _e;                                                                  \
  }

  // step t=1 = hi of pair 0
  SC(HIDW(u0.x), HIDW(u0.y), HIDW(u0.z), HIDW(u0.w));

  uint4 b0, b1, b2, b3, b4, b5, b6, b7, b8, b9, b10, b11, b12, b13, b14, b15;
  LOADP(b0, 1);  LOADP(b1, 2);  LOADP(b2, 3);  LOADP(b3, 4);
  LOADP(b4, 5);  LOADP(b5, 6);  LOADP(b6, 7);  LOADP(b7, 8);
  LOADP(b8, 9);  LOADP(b9, 10); LOADP(b10, 11); LOADP(b11, 12);
  LOADP(b12, 13); LOADP(b13, 14); LOADP(b14, 15); LOADP(b15, 16);

  int k = 1;  // pair k covers steps 2k, 2k+1
  for (; 2 * k + 32 <= F; k += 16) {
    PAIRP(b0, k + 16); PAIRP(b1, k + 17); PAIRP(b2, k + 18); PAIRP(b3, k + 19);
    PAIRP(b4, k + 20); PAIRP(b5, k + 21); PAIRP(b6, k + 22); PAIRP(b7, k + 23);
    RESCALE;
    PAIRP(b8, k + 24);  PAIRP(b9, k + 25);  PAIRP(b10, k + 26); PAIRP(b11, k + 27);
    PAIRP(b12, k + 28); PAIRP(b13, k + 29); PAIRP(b14, k + 30); PAIRP(b15, k + 31);
    RESCALE;
  }
  // tail: <=15 pairs + possible lone lo; ring holds pairs k..k+15 in b0..b15
  TPAIR(b0); TPAIR(b1); TPAIR(b2); TPAIR(b3);
  TPAIR(b4); TPAIR(b5); TPAIR(b6); TPAIR(b7);
  RESCALE;
  TPAIR(b8);  TPAIR(b9);  TPAIR(b10); TPAIR(b11);
  TPAIR(b12); TPAIR(b13); TPAIR(b14); TPAIR(b15);

  __shared__ double sa[256];
  sa[4 * lane + 0] = a0;
  sa[4 * lane + 1] = a1;
  sa[4 * lane + 2] = a2;
  sa[4 * lane + 3] = a3;
  __syncthreads();
  if (lane == 0) {
    int yl = y_len[b];
    int idx2 = (2 * yl - 1 > 0) ? (2 * yl - 1) : 0;
    double s = sa[2 * yl] + sa[idx2];
    double loss = ((double)K - log2(s)) * LN2D;  // -ln(alpha_true)
    losses[b] = (float)loss;
  }
}

// Kernel 3: zero_infinity + mean over B.
__global__ __launch_bounds__(64) void k_final(const float* __restrict__ losses,
                                              float* __restrict__ out)
{
  int tid = threadIdx.x;
  float v = (tid < Bc) ? losses[tid] : 0.f;
  if (!(v < 1e29f)) v = 0.f;  // inf/nan -> 0 (zero_infinity)
#pragma unroll
  for (int off = 32; off; off >>= 1) v += __shfl_xor(v, off);
  if (tid == 0) out[0] = v / (float)Bc;
}

extern "C" void kernel_launch(void* const* d_in, const int* in_sizes, int n_in,
                              void* d_out, int out_size, void* d_ws, size_t ws_size,
                              hipStream_t stream) {
  const float* x = (const float*)d_in[0];      // [B,T,V] f32
  const int* y = (const int*)d_in[1];          // [B,S]
  const int* f_len = (const int*)d_in[2];      // [B]
  const int* y_len = (const int*)d_in[3];      // [B]
  float* out = (float*)d_out;                  // scalar f32
  __hip_bfloat16* pp = (__hip_bfloat16*)d_ws;  // [B,TP,256,2] bf16 = 8.19 MB
  float* losses = (float*)((char*)d_ws + (size_t)Bc * TP * 1024);

  k_prob_gather<<<dim3(Bc * Tc), dim3(256), 0, stream>>>(x, y, f_len, pp);
  k_ctc_dp<<<dim3(Bc), dim3(64), 0, stream>>>(pp, y, f_len, y_len, losses);
  k_final<<<dim3(1), dim3(64), 0, stream>>>(losses, out);
}

// Round 11
// 75.016 us; speedup vs baseline: 4.2579x; 1.4329x over previous
//
#include <hip/hip_runtime.h>
#include <hip/hip_bf16.h>

#define LN2D 0.6931471805599453

constexpr int Bc = 16, Tc = 1000, Vc = 4096, Sc = 100;
constexpr int TP = Tc / 2;  // 500 time-pairs; pp[b][tp][s(256)][t&1] bf16

// Kernel 1: per (b,t) softmax over V, gather the 201 extended-label probs
// (LINEAR domain) as bf16 into pp[b][t>>1][s][t&1]. (round-10, PASSED)
__global__ __launch_bounds__(256) void k_prob_gather(
    const float* __restrict__ x, const int* __restrict__ y,
    const int* __restrict__ f_len, __hip_bfloat16* __restrict__ pp)
{
  int bt = blockIdx.x;  // b*T + t
  int b = bt / Tc;
  int t = bt - b * Tc;
  if (t >= f_len[b]) return;
  int tid = threadIdx.x;
  const float4* row4 = (const float4*)(x + (size_t)bt * Vc);
  __shared__ float sh[Vc];
  __shared__ float red[8];
  float4* sh4 = (float4*)sh;
  float4 v[4];
  float mx = -3.4e38f;
#pragma unroll
  for (int k = 0; k < 4; ++k) {
    v[k] = row4[k * 256 + tid];
    sh4[k * 256 + tid] = v[k];
    mx = fmaxf(mx, fmaxf(fmaxf(v[k].x, v[k].y), fmaxf(v[k].z, v[k].w)));
  }
#pragma unroll
  for (int off = 32; off; off >>= 1) mx = fmaxf(mx, __shfl_xor(mx, off));
  if ((tid & 63) == 0) red[tid >> 6] = mx;
  __syncthreads();
  mx = fmaxf(fmaxf(red[0], red[1]), fmaxf(red[2], red[3]));
  float s = 0.f;
#pragma unroll
  for (int k = 0; k < 4; ++k) {
    s += __expf(v[k].x - mx) + __expf(v[k].y - mx) +
         __expf(v[k].z - mx) + __expf(v[k].w - mx);
  }
#pragma unroll
  for (int off = 32; off; off >>= 1) s += __shfl_xor(s, off);
  if ((tid & 63) == 0) red[4 + (tid >> 6)] = s;
  __syncthreads();
  s = (red[4] + red[5]) + (red[6] + red[7]);
  float lse = mx + __logf(s);
  float p;
  if (tid <= 200) {
    int lab = (tid & 1) ? y[b * Sc + (tid >> 1)] : 0;  // z[s]: blank at even s
    p = __expf(sh[lab] - lse);
  } else {
    p = 0.f;  // dead states
  }
  pp[(size_t)b * (TP * 512) + (size_t)(t >> 1) * 512 + tid * 2 + (t & 1)] =
      __float2bfloat16(p);
}

// DPP whole-wave shifts (VALU pipe, no lgkm). wave_shr:1 (0x138): lane n <-
// lane n-1, lane 0 <- old=0 (empirically verified, rounds 9/10 PASSED).
// wave_shl:1 (0x130): mirror, lane n <- lane n+1, lane 63 <- old=0.
__device__ __forceinline__ double dpp_wshr1_f64(double x) {
  int lo = __double2loint(x), hi = __double2hiint(x);
  lo = __builtin_amdgcn_update_dpp(0, lo, 0x138, 0xF, 0xF, false);
  hi = __builtin_amdgcn_update_dpp(0, hi, 0x138, 0xF, 0xF, false);
  return __hiloint2double(hi, lo);
}
__device__ __forceinline__ double dpp_wshl1_f64(double x) {
  int lo = __double2loint(x), hi = __double2hiint(x);
  lo = __builtin_amdgcn_update_dpp(0, lo, 0x130, 0xF, 0xF, false);
  hi = __builtin_amdgcn_update_dpp(0, hi, 0x130, 0xF, 0xF, false);
  return __hiloint2double(hi, lo);
}

// Kernel 2: CTC DP split fwd/bwd at mid=F/2 — 32 one-wave blocks (b=blk>>1,
// dir=blk&1). Forward (R10 body, PASSED): alpha_mid via steps 1..mid.
// Backward: beta_mid^T = c^T M_{F-1}..M_{mid+1} via the transposed banded
// recurrence (same cost; cross-lane is a SAME-step wave_shl of the pre-sum
// q = tmp0 + allow1*tmp1 from lane+1; even states need no cross-lane term).
// Both: f64 state, bf16 prob pairs, 16-deep ring, exact 2^e rescale / 16
// steps (rounds 6-10 numerics). loss = (Kf+Kb - log2(beta.alpha)) * ln2.
__global__ __launch_bounds__(64) void k_ctc_dp(
    const __hip_bfloat16* __restrict__ pp, const int* __restrict__ y,
    const int* __restrict__ f_len, const int* __restrict__ y_len,
    double* __restrict__ aw, double* __restrict__ bw,
    int* __restrict__ Kf, int* __restrict__ Kb)
{
  int b = blockIdx.x >> 1;
  int dir = blockIdx.x & 1;
  int lane = threadIdx.x;
  const uint4* pbp = (const uint4*)(pp + (size_t)b * (TP * 512));  // 64/pair
  int F = f_len[b];
  int mid = F >> 1;
  const int* yb = y + b * Sc;
  int i0 = 2 * lane, i1i = 2 * lane + 1;
  int y_m1 = (i0 >= 1 && i0 - 1 < Sc) ? yb[i0 - 1] : -1;
  int y_0  = (i0 < Sc) ? yb[i0] : -2;
  int y_1  = (i1i < Sc) ? yb[i1i] : -3;
  bool allow1 = (y_0 != y_m1);   // allow[4L+1]
  bool allow3 = (y_1 != y_0);    // allow[4L+3]
  int K = 0;

#define LODW(W) ((double)__int_as_float((int)((W) << 16)))
#define HIDW(W) ((double)__int_as_float((int)((W) & 0xffff0000u)))
#define RORMAXI(M, CTRL)                                                      \
  {                                                                           \
    int _t = __builtin_amdgcn_update_dpp(0, (M), (CTRL), 0xF, 0xF, false);    \
    (M) = (_t > (M)) ? _t : (M);                                              \
  }

  if (dir == 0) {
    // ---------------- forward: steps t = 1..mid ----------------
    int E = mid + 1;  // consume t < E
    uint4 u0 = pbp[lane];
    double a0 = (lane == 0) ? LODW(u0.x) : 0.0;
    double a1 = (lane == 0) ? LODW(u0.y) : 0.0;
    double a2 = 0.0, a3 = 0.0;
    double un = 0.0;

#define SC(PX, PY, PZ, PW)                                                    \
  {                                                                           \
    double u = (lane == 0) ? 0.0 : un;                                        \
    double n0 = (a0 + u) * (PX);                                              \
    double n1 = (a1 + a0 + (allow1 ? u : 0.0)) * (PY);                        \
    double n2 = (a2 + a1) * (PZ);                                             \
    double n3 = (a3 + a2 + (allow3 ? a1 : 0.0)) * (PW);                       \
    un = dpp_wshr1_f64(n3);                                                   \
    a0 = n0; a1 = n1; a2 = n2; a3 = n3;                                       \
  }
#define LOADPF(B, T)                                                          \
  {                                                                           \
    int tt = (T); tt = tt < TP ? tt : (TP - 1);                               \
    B = pbp[(size_t)tt * 64 + lane];                                          \
  }
#define PAIRP(B, TN)                                                          \
  {                                                                           \
    uint4 c = B; LOADPF(B, TN);                                               \
    SC(LODW(c.x), LODW(c.y), LODW(c.z), LODW(c.w));                           \
    SC(HIDW(c.x), HIDW(c.y), HIDW(c.z), HIDW(c.w));                           \
  }
#define TPAIR(B)                                                              \
  if (2 * k < E) {                                                            \
    uint4 c = B;                                                              \
    SC(LODW(c.x), LODW(c.y), LODW(c.z), LODW(c.w));                           \
    if (2 * k + 1 < E) { SC(HIDW(c.x), HIDW(c.y), HIDW(c.z), HIDW(c.w)); }    \
    ++k;                                                                      \
  }
#define RESCALE_F                                                             \
  {                                                                           \
    int _h = max(max(__double2hiint(a0), __double2hiint(a1)),                 \
                 max(__double2hiint(a2), __double2hiint(a3)));                \
    RORMAXI(_h, 0x121); RORMAXI(_h, 0x122);                                   \
    RORMAXI(_h, 0x124); RORMAXI(_h, 0x128);                                   \
    int _g = max(max(__builtin_amdgcn_readlane(_h, 0),                        \
                     __builtin_amdgcn_readlane(_h, 16)),                      \
                 max(__builtin_amdgcn_readlane(_h, 32),                       \
                     __builtin_amdgcn_readlane(_h, 48)));                     \
    int _e = (_g >> 20) - 1279;                                               \
    double _sc = __hiloint2double((1023 - _e) << 20, 0);                      \
    a0 *= _sc; a1 *= _sc; a2 *= _sc; a3 *= _sc; un *= _sc;                    \
    K -= _e;                                                                  \
  }

    SC(HIDW(u0.x), HIDW(u0.y), HIDW(u0.z), HIDW(u0.w));  // t = 1

    uint4 b0, b1, b2, b3, b4, b5, b6, b7, b8, b9, b10, b11, b12, b13, b14, b15;
    LOADPF(b0, 1);  LOADPF(b1, 2);   LOADPF(b2, 3);   LOADPF(b3, 4);
    LOADPF(b4, 5);  LOADPF(b5, 6);   LOADPF(b6, 7);   LOADPF(b7, 8);
    LOADPF(b8, 9);  LOADPF(b9, 10);  LOADPF(b10, 11); LOADPF(b11, 12);
    LOADPF(b12, 13); LOADPF(b13, 14); LOADPF(b14, 15); LOADPF(b15, 16);

    int k = 1;
    for (; 2 * k + 32 <= E; k += 16) {
      PAIRP(b0, k + 16); PAIRP(b1, k + 17); PAIRP(b2, k + 18); PAIRP(b3, k + 19);
      PAIRP(b4, k + 20); PAIRP(b5, k + 21); PAIRP(b6, k + 22); PAIRP(b7, k + 23);
      RESCALE_F;
      PAIRP(b8, k + 24);  PAIRP(b9, k + 25);  PAIRP(b10, k + 26); PAIRP(b11, k + 27);
      PAIRP(b12, k + 28); PAIRP(b13, k + 29); PAIRP(b14, k + 30); PAIRP(b15, k + 31);
      RESCALE_F;
    }
    TPAIR(b0); TPAIR(b1); TPAIR(b2); TPAIR(b3);
    TPAIR(b4); TPAIR(b5); TPAIR(b6); TPAIR(b7);
    RESCALE_F;
    TPAIR(b8);  TPAIR(b9);  TPAIR(b10); TPAIR(b11);
    TPAIR(b12); TPAIR(b13); TPAIR(b14); TPAIR(b15);

    double* A = aw + b * 256 + 4 * lane;
    A[0] = a0; A[1] = a1; A[2] = a2; A[3] = a3;
    if (lane == 0) Kf[b] = K;
  } else {
    // ---------------- backward: steps t = F-1 down to mid+1 ----------------
    int stop = mid + 1;
    int yl = y_len[b];
    int idx1 = 2 * yl;
    int idx2 = (2 * yl - 1 > 0) ? (2 * yl - 1) : 0;
    int s0 = 4 * lane;
    double bb0 = (s0 == idx1 || s0 == idx2) ? 1.0 : 0.0;
    double bb1 = (s0 + 1 == idx1 || s0 + 1 == idx2) ? 1.0 : 0.0;
    double bb2 = (s0 + 2 == idx1 || s0 + 2 == idx2) ? 1.0 : 0.0;
    double bb3 = (s0 + 3 == idx1 || s0 + 3 == idx2) ? 1.0 : 0.0;

#define BC(PX, PY, PZ, PW)                                                    \
  {                                                                           \
    double t0 = bb0 * (PX), t1 = bb1 * (PY);                                  \
    double t2 = bb2 * (PZ), t3 = bb3 * (PW);                                  \
    double q = t0 + (allow1 ? t1 : 0.0);                                      \
    double qs = dpp_wshl1_f64(q); /* from lane+1; lane63 -> 0 */              \
    bb0 = t0 + t1;                                                            \
    bb1 = t1 + t2 + (allow3 ? t3 : 0.0);                                      \
    bb2 = t2 + t3;                                                            \
    bb3 = t3 + qs;                                                            \
  }
#define LOADPB(B, T)                                                          \
  {                                                                           \
    int tt = (T); tt = tt > 0 ? tt : 0;                                       \
    B = pbp[(size_t)tt * 64 + lane];                                          \
  }
#define BPAIRP(B, TN)                                                         \
  {                                                                           \
    uint4 c = B; LOADPB(B, TN);                                               \
    BC(HIDW(c.x), HIDW(c.y), HIDW(c.z), HIDW(c.w));                           \
    BC(LODW(c.x), LODW(c.y), LODW(c.z), LODW(c.w));                           \
  }
#define BTPAIR(B)                                                             \
  {                                                                           \
    uint4 c = B;                                                              \
    if (2 * kb + 1 >= stop) { BC(HIDW(c.x), HIDW(c.y), HIDW(c.z), HIDW(c.w)); } \
    if (2 * kb >= stop) { BC(LODW(c.x), LODW(c.y), LODW(c.z), LODW(c.w)); }   \
    --kb;                                                                     \
  }
#define RESCALE_B                                                             \
  {                                                                           \
    int _h = max(max(__double2hiint(bb0), __double2hiint(bb1)),               \
                 max(__double2hiint(bb2), __double2hiint(bb3)));              \
    RORMAXI(_h, 0x121); RORMAXI(_h, 0x122);                                   \
    RORMAXI(_h, 0x124); RORMAXI(_h, 0x128);                                   \
    int _g = max(max(__builtin_amdgcn_readlane(_h, 0),                        \
                     __builtin_amdgcn_readlane(_h, 16)),                      \
                 max(__builtin_amdgcn_readlane(_h, 32),                       \
                     __builtin_amdgcn_readlane(_h, 48)));                     \
    int _e = (_g >> 20) - 1279;                                               \
    double _sc = __hiloint2double((1023 - _e) << 20, 0);                      \
    bb0 *= _sc; bb1 *= _sc; bb2 *= _sc; bb3 *= _sc;                           \
    K -= _e;                                                                  \
  }

    int kb = (F - 1) >> 1;
    if (((F - 1) & 1) == 0) {  // top pair partial: only lo (t=F-1) exists
      uint4 c = pbp[(size_t)kb * 64 + lane];
      BC(LODW(c.x), LODW(c.y), LODW(c.z), LODW(c.w));
      --kb;
    }
    uint4 c0, c1, c2, c3, c4, c5, c6, c7, c8, c9, c10, c11, c12, c13, c14, c15;
    LOADPB(c0, kb);      LOADPB(c1, kb - 1);  LOADPB(c2, kb - 2);  LOADPB(c3, kb - 3);
    LOADPB(c4, kb - 4);  LOADPB(c5, kb - 5);  LOADPB(c6, kb - 6);  LOADPB(c7, kb - 7);
    LOADPB(c8, kb - 8);  LOADPB(c9, kb - 9);  LOADPB(c10, kb - 10); LOADPB(c11, kb - 11);
    LOADPB(c12, kb - 12); LOADPB(c13, kb - 13); LOADPB(c14, kb - 14); LOADPB(c15, kb - 15);

    for (; 2 * (kb - 15) >= stop; kb -= 16) {
      BPAIRP(c0, kb - 16); BPAIRP(c1, kb - 17); BPAIRP(c2, kb - 18); BPAIRP(c3, kb - 19);
      BPAIRP(c4, kb - 20); BPAIRP(c5, kb - 21); BPAIRP(c6, kb - 22); BPAIRP(c7, kb - 23);
      RESCALE_B;
      BPAIRP(c8, kb - 24);  BPAIRP(c9, kb - 25);  BPAIRP(c10, kb - 26); BPAIRP(c11, kb - 27);
      BPAIRP(c12, kb - 28); BPAIRP(c13, kb - 29); BPAIRP(c14, kb - 30); BPAIRP(c15, kb - 31);
      RESCALE_B;
    }
    BTPAIR(c0); BTPAIR(c1); BTPAIR(c2); BTPAIR(c3);
    BTPAIR(c4); BTPAIR(c5); BTPAIR(c6); BTPAIR(c7);
    RESCALE_B;
    BTPAIR(c8);  BTPAIR(c9);  BTPAIR(c10); BTPAIR(c11);
    BTPAIR(c12); BTPAIR(c13); BTPAIR(c14); BTPAIR(c15);

    double* Bp = bw + b * 256 + 4 * lane;
    Bp[0] = bb0; Bp[1] = bb1; Bp[2] = bb2; Bp[3] = bb3;
    if (lane == 0) Kb[b] = K;
  }
}

// Kernel 3: per-batch dot(beta_mid, alpha_mid) -> loss; zero_infinity + mean.
__global__ __launch_bounds__(1024) void k_combine(
    const double* __restrict__ aw, const double* __restrict__ bw,
    const int* __restrict__ Kf, const int* __restrict__ Kb,
    float* __restrict__ out)
{
  int w = threadIdx.x >> 6, lane = threadIdx.x & 63;
  const double* A = aw + w * 256 + 4 * lane;
  const double* Bv = bw + w * 256 + 4 * lane;
  double s = A[0] * Bv[0] + A[1] * Bv[1] + A[2] * Bv[2] + A[3] * Bv[3];
#pragma unroll
  for (int off = 32; off; off >>= 1) s += __shfl_xor(s, off);
  __shared__ float sl[16];
  if (lane == 0) {
    double loss = ((double)(Kf[w] + Kb[w]) - log2(s)) * LN2D;
    float lf = (float)loss;
    if (!(lf < 1e29f)) lf = 0.f;  // inf/nan -> 0 (zero_infinity)
    sl[w] = lf;
  }
  __syncthreads();
  if (threadIdx.x < 64) {
    float v = (lane < 16) ? sl[lane] : 0.f;
#pragma unroll
    for (int off = 32; off; off >>= 1) v += __shfl_xor(v, off);
    if (lane == 0) out[0] = v / (float)Bc;
  }
}

extern "C" void kernel_launch(void* const* d_in, const int* in_sizes, int n_in,
                              void* d_out, int out_size, void* d_ws, size_t ws_size,
                              hipStream_t stream) {
  const float* x = (const float*)d_in[0];      // [B,T,V] f32
  const int* y = (const int*)d_in[1];          // [B,S]
  const int* f_len = (const int*)d_in[2];      // [B]
  const int* y_len = (const int*)d_in[3];      // [B]
  float* out = (float*)d_out;                  // scalar f32
  __hip_bfloat16* pp = (__hip_bfloat16*)d_ws;  // [B,TP,256,2] bf16 = 8.19 MB
  size_t ppb = (size_t)Bc * TP * 1024;         // bytes
  double* aw = (double*)((char*)d_ws + ppb);   // [B,256] f64
  double* bw = aw + Bc * 256;                  // [B,256] f64
  int* Kf = (int*)(bw + Bc * 256);             // [B]
  int* Kb = Kf + Bc;                           // [B]

  k_prob_gather<<<dim3(Bc * Tc), dim3(256), 0, stream>>>(x, y, f_len, pp);
  k_ctc_dp<<<dim3(2 * Bc), dim3(64), 0, stream>>>(pp, y, f_len, y_len, aw, bw, Kf, Kb);
  k_combine<<<dim3(1), dim3(1024), 0, stream>>>(aw, bw, Kf, Kb, out);
}